// Round 1
// baseline (543.696 us; speedup 1.0000x reference)
//
#include <hip/hip_runtime.h>

#define N_NODES 20000
#define N_EDGES 640000
#define D 128
#define TM 64   // GEMM tile rows per block

// ---------------- CSR build ----------------

__global__ void zero_counts_kernel(int* counts) {
    int i = blockIdx.x * blockDim.x + threadIdx.x;
    if (i < N_NODES) counts[i] = 0;
}

__global__ void count_deg_kernel(const int* __restrict__ dst, int* __restrict__ counts) {
    int e = blockIdx.x * blockDim.x + threadIdx.x;
    if (e < N_EDGES) atomicAdd(&counts[dst[e]], 1);
}

// Single-block exclusive scan over 20000 degree counts -> offsets, and init cursor.
__global__ void scan_offsets_kernel(const int* __restrict__ counts,
                                    int* __restrict__ offsets,
                                    int* __restrict__ cursor) {
    __shared__ int partial[256];
    int t = threadIdx.x;
    const int CH = (N_NODES + 255) / 256;  // 79 nodes per thread
    int lo = t * CH;
    int hi = lo + CH; if (hi > N_NODES) hi = N_NODES;
    int s = 0;
    for (int i = lo; i < hi; ++i) s += counts[i];
    partial[t] = s;
    __syncthreads();
    // Hillis-Steele inclusive scan of the 256 partials
    for (int off = 1; off < 256; off <<= 1) {
        int v = (t >= off) ? partial[t - off] : 0;
        __syncthreads();
        partial[t] += v;
        __syncthreads();
    }
    int run = (t == 0) ? 0 : partial[t - 1];
    for (int i = lo; i < hi; ++i) {
        int c = counts[i];
        offsets[i] = run;
        cursor[i]  = run;
        run += c;
    }
    if (t == 255) offsets[N_NODES] = run;  // == N_EDGES
}

__global__ void scatter_edges_kernel(const int* __restrict__ src, const int* __restrict__ dst,
                                     int* __restrict__ cursor, int* __restrict__ srcsort) {
    int e = blockIdx.x * blockDim.x + threadIdx.x;
    if (e < N_EDGES) {
        int p = atomicAdd(&cursor[dst[e]], 1);
        srcsort[p] = src[e];
    }
}

// ---------------- per-layer: aggregation  x[i] = h[i] + sum_{j->i} h[j] ----------------

__global__ __launch_bounds__(128) void agg_kernel(const float* __restrict__ hin,
                                                  const int* __restrict__ offsets,
                                                  const int* __restrict__ srcsort,
                                                  float* __restrict__ x) {
    int node = blockIdx.x;
    int f = threadIdx.x;
    float acc = hin[node * D + f];
    int lo = offsets[node];
    int hi = offsets[node + 1];
    for (int k = lo; k < hi; ++k) {
        int s = srcsort[k];   // uniform across block -> broadcast
        acc += hin[s * D + f];
    }
    x[node * D + f] = acc;
}

// ---------------- per-layer: out = x @ W + b  (x: N x 128, W: 128 x 128) ----------------

__global__ __launch_bounds__(256) void gemm_kernel(const float* __restrict__ x,
                                                   const float* __restrict__ W,
                                                   const float* __restrict__ bias,
                                                   float* __restrict__ out) {
    __shared__ float Xs[TM][D];  // 32 KB
    int t = threadIdx.x;
    int row0 = blockIdx.x * TM;
    int nrows = N_NODES - row0; if (nrows > TM) nrows = TM;

    // load X tile (vectorized, coalesced)
    for (int i = t; i < nrows * (D / 4); i += 256) {
        int r  = i / (D / 4);
        int c4 = i % (D / 4);
        ((float4*)&Xs[r][0])[c4] = ((const float4*)&x[(size_t)(row0 + r) * D])[c4];
    }
    __syncthreads();

    int cg = t & 31;   // 32 col-groups of 4 cols
    int rg = t >> 5;   // 8 row-groups of 8 rows
    int j0 = cg * 4;
    int r0 = rg * 8;

    float acc[8][4];
    float4 bb = *((const float4*)&bias[j0]);
    #pragma unroll
    for (int i = 0; i < 8; ++i) {
        acc[i][0] = bb.x; acc[i][1] = bb.y; acc[i][2] = bb.z; acc[i][3] = bb.w;
    }

    for (int k = 0; k < D; ++k) {
        float4 w = *((const float4*)&W[k * D + j0]);  // coalesced across col-groups
        #pragma unroll
        for (int i = 0; i < 8; ++i) {
            float xv = Xs[r0 + i][k];  // half-wave broadcast (2-way, free)
            acc[i][0] += xv * w.x;
            acc[i][1] += xv * w.y;
            acc[i][2] += xv * w.z;
            acc[i][3] += xv * w.w;
        }
    }

    #pragma unroll
    for (int i = 0; i < 8; ++i) {
        int r = r0 + i;
        if (r < nrows) {
            *((float4*)&out[(size_t)(row0 + r) * D + j0]) =
                make_float4(acc[i][0], acc[i][1], acc[i][2], acc[i][3]);
        }
    }
}

// ---------------- launch ----------------

extern "C" void kernel_launch(void* const* d_in, const int* in_sizes, int n_in,
                              void* d_out, int out_size, void* d_ws, size_t ws_size,
                              hipStream_t stream) {
    const float* h   = (const float*)d_in[0];
    const int*   ei  = (const int*)d_in[1];
    const int*   src = ei;
    const int*   dst = ei + N_EDGES;
    const float* Wm[4] = {(const float*)d_in[2], (const float*)d_in[4],
                          (const float*)d_in[6], (const float*)d_in[8]};
    const float* Bv[4] = {(const float*)d_in[3], (const float*)d_in[5],
                          (const float*)d_in[7], (const float*)d_in[9]};
    float* out = (float*)d_out;

    char* ws = (char*)d_ws;
    auto alloc = [&](size_t bytes) {
        char* p = ws;
        ws += (bytes + 255) & ~(size_t)255;
        return p;
    };
    int*   counts  = (int*)alloc(N_NODES * sizeof(int));
    int*   offsets = (int*)alloc((N_NODES + 1) * sizeof(int));
    int*   cursor  = (int*)alloc(N_NODES * sizeof(int));
    int*   srcsort = (int*)alloc(N_EDGES * sizeof(int));
    float* bufA    = (float*)alloc((size_t)N_NODES * D * sizeof(float));
    float* bufB    = (float*)alloc((size_t)N_NODES * D * sizeof(float));

    // CSR build (edge_index is constant across layers -> build once per call)
    zero_counts_kernel<<<(N_NODES + 255) / 256, 256, 0, stream>>>(counts);
    count_deg_kernel<<<(N_EDGES + 255) / 256, 256, 0, stream>>>(dst, counts);
    scan_offsets_kernel<<<1, 256, 0, stream>>>(counts, offsets, cursor);
    scatter_edges_kernel<<<(N_EDGES + 255) / 256, 256, 0, stream>>>(src, dst, cursor, srcsort);

    // 4 GIN layers
    const float* cur = h;
    for (int l = 0; l < 4; ++l) {
        agg_kernel<<<N_NODES, 128, 0, stream>>>(cur, offsets, srcsort, bufA);
        float* o = (l == 3) ? out : bufB;
        gemm_kernel<<<(N_NODES + TM - 1) / TM, 256, 0, stream>>>(bufA, Wm[l], Bv[l], o);
        cur = o;
    }
}